// Round 12
// baseline (42.602 us; speedup 1.0000x reference)
//
#include <hip/hip_runtime.h>
#include <math.h>

#define NROWS 128
#define KDIM  1024
#define ODIM  512
#define NB    32
#define BS    32

__device__ __forceinline__ int clz32(unsigned x) { return x ? __builtin_clz(x) : 32; }

// FROZEN SEMANTICS (r7-r11): kept = P - ((t&m)-(h&m)), m = 2^drop-1, h=P>>1,
// t=P+h, drop = clamp(isum - clz((t^h)|1), 0, 31), P = ix*iw, isum = intra + s.
// Whole per-element pipeline in ONE asm block per element-pair: extracts, mul24,
// isum, naf core, accumulate. No compiler freedom (r3/r4/r6 mis-folds; r9 vs r11
// absmax delta proved even intrinsic forms get perturbed).
// %0=bacc(+v)  %1..%5 scratch  %6=xw  %7=ww  %8=s
// OFF0/OFF1: byte offsets of the two w elements within ww (string immediates).
#define NAF_PAIR(BACC, XW, WW, SS, OFF0, OFF1)                         \
  asm("v_bfe_i32     %1, %6, 0, 8\n\t"      /* ix0            */       \
      "v_bfe_i32     %2, %7, " OFF0 ", 8\n\t" /* iw0           */      \
      "v_mul_i32_i24 %1, %1, %2\n\t"        /* P0             */       \
      "v_bfe_u32     %2, %6, 8, 8\n\t"      /* in0            */       \
      "v_add_u32     %2, %8, %2\n\t"        /* isum0 = s+in0  */       \
      "v_ashrrev_i32 %3, 1, %1\n\t"         /* h0             */       \
      "v_add_u32     %4, %1, %3\n\t"        /* t0             */       \
      "v_xor_b32     %5, %4, %3\n\t"        /* c = t^h        */       \
      "v_or_b32      %5, 1, %5\n\t"                                     \
      "v_ffbh_u32    %5, %5\n\t"            /* clz            */       \
      "v_sub_u32     %2, %2, %5\n\t"        /* dr = isum-clz  */       \
      "v_med3_i32    %2, %2, 0, 31\n\t"                                 \
      "v_bfe_u32     %5, %4, 0, %2\n\t"     /* t&m            */       \
      "v_bfe_u32     %3, %3, 0, %2\n\t"     /* h&m            */       \
      "v_sub_u32     %5, %5, %3\n\t"        /* dropped        */       \
      "v_sub_u32     %1, %1, %5\n\t"        /* kept0          */       \
      "v_add_u32     %0, %0, %1\n\t"        /* bacc += kept0  */       \
      "v_bfe_i32     %1, %6, 16, 8\n\t"     /* ix1            */       \
      "v_bfe_i32     %2, %7, " OFF1 ", 8\n\t" /* iw1           */      \
      "v_mul_i32_i24 %1, %1, %2\n\t"        /* P1             */       \
      "v_bfe_u32     %2, %6, 24, 8\n\t"     /* in1            */       \
      "v_add_u32     %2, %8, %2\n\t"        /* isum1          */       \
      "v_ashrrev_i32 %3, 1, %1\n\t"                                     \
      "v_add_u32     %4, %1, %3\n\t"                                    \
      "v_xor_b32     %5, %4, %3\n\t"                                    \
      "v_or_b32      %5, 1, %5\n\t"                                     \
      "v_ffbh_u32    %5, %5\n\t"                                        \
      "v_sub_u32     %2, %2, %5\n\t"                                    \
      "v_med3_i32    %2, %2, 0, 31\n\t"                                 \
      "v_bfe_u32     %5, %4, 0, %2\n\t"                                 \
      "v_bfe_u32     %3, %3, 0, %2\n\t"                                 \
      "v_sub_u32     %5, %5, %3\n\t"                                    \
      "v_sub_u32     %1, %1, %5\n\t"        /* kept1          */       \
      "v_add_u32     %0, %0, %1"            /* bacc += kept1  */       \
      : "+v"(BACC), "=&v"(sc0), "=&v"(sc1), "=&v"(sc2), "=&v"(sc3),    \
        "=&v"(sc4)                                                      \
      : "v"(XW), "v"(WW), "v"(SS))

// ---------------- merged prep (r9/r11-identical): blocks 0..15 x, 16..79 w
__global__ void prep_kernel(const float* __restrict__ x, const float* __restrict__ wgt,
                            unsigned short* __restrict__ xp, unsigned char* __restrict__ wq,
                            float* __restrict__ xs, float* __restrict__ lxs,
                            float* __restrict__ wsc, float* __restrict__ lws) {
  const int bid = blockIdx.x;
  if (bid < 16) {
    int tid = bid * 256 + threadIdx.x;            // 0..4095 = 128 rows x 32 blocks
    int row = tid >> 5, blk = tid & 31;
    const float4* p = (const float4*)(x + (size_t)row * KDIM + blk * BS);
    float v[32];
    float m = 0.f;
#pragma unroll
    for (int i = 0; i < 8; ++i) {
      float4 f = p[i];
      v[4*i+0] = f.x; v[4*i+1] = f.y; v[4*i+2] = f.z; v[4*i+3] = f.w;
      m = fmaxf(m, fmaxf(fmaxf(fabsf(f.x), fabsf(f.y)), fmaxf(fabsf(f.z), fabsf(f.w))));
    }
    float scale = fmaxf(m / 1.984375f, 1e-30f);
    int q[32], e[32], emax = -60;
#pragma unroll
    for (int i = 0; i < 32; ++i) {
      float t = v[i] / scale * 64.0f;     // IEEE div + exact pow2 mul, matches ref
      int qi = (int)rintf(t);             // round-half-even, matches jnp.round
      q[i] = qi;
      int a = qi < 0 ? -qi : qi;
      int ei = a ? (31 - clz32((unsigned)a)) - 6 : -60;
      e[i] = ei;
      emax = ei > emax ? ei : emax;
    }
    unsigned short u[32];
#pragma unroll
    for (int i = 0; i < 32; ++i)
      u[i] = (unsigned short)(((emax - e[i]) << 8) | (q[i] & 0xFF));
    uint4* dst = (uint4*)(xp + (size_t)row * KDIM + blk * BS);
#pragma unroll
    for (int i = 0; i < 4; ++i) {
      uint4 w4;
      w4.x = (unsigned)u[8*i+0] | ((unsigned)u[8*i+1] << 16);
      w4.y = (unsigned)u[8*i+2] | ((unsigned)u[8*i+3] << 16);
      w4.z = (unsigned)u[8*i+4] | ((unsigned)u[8*i+5] << 16);
      w4.w = (unsigned)u[8*i+6] | ((unsigned)u[8*i+7] << 16);
      dst[i] = w4;
    }
    xs[tid] = scale;
    lxs[tid] = (float)log2((double)scale);
  } else {
    int tid = (bid - 16) * 256 + threadIdx.x;     // 0..16383 = 512 rows x 32 blocks
    int row = tid >> 5, blk = tid & 31;
    const float4* p = (const float4*)(wgt + (size_t)row * KDIM + blk * BS);
    float v[32];
    float m = 0.f;
#pragma unroll
    for (int i = 0; i < 8; ++i) {
      float4 f = p[i];
      v[4*i+0] = f.x; v[4*i+1] = f.y; v[4*i+2] = f.z; v[4*i+3] = f.w;
      m = fmaxf(m, fmaxf(fmaxf(fabsf(f.x), fabsf(f.y)), fmaxf(fabsf(f.z), fabsf(f.w))));
    }
    float scale = fmaxf(m / 1.984375f, 1e-30f);
    unsigned char c[32];
#pragma unroll
    for (int i = 0; i < 32; ++i) {
      float t = v[i] / scale * 64.0f;
      int qi = (int)rintf(t);
      c[i] = (unsigned char)(qi & 0xFF);
    }
    uint4* dst = (uint4*)(wq + (size_t)row * KDIM + blk * BS);
#pragma unroll
    for (int i = 0; i < 2; ++i) {
      uint4 w4;
      w4.x = (unsigned)c[16*i+ 0] | ((unsigned)c[16*i+ 1] << 8) | ((unsigned)c[16*i+ 2] << 16) | ((unsigned)c[16*i+ 3] << 24);
      w4.y = (unsigned)c[16*i+ 4] | ((unsigned)c[16*i+ 5] << 8) | ((unsigned)c[16*i+ 6] << 16) | ((unsigned)c[16*i+ 7] << 24);
      w4.z = (unsigned)c[16*i+ 8] | ((unsigned)c[16*i+ 9] << 8) | ((unsigned)c[16*i+10] << 16) | ((unsigned)c[16*i+11] << 24);
      w4.w = (unsigned)c[16*i+12] | ((unsigned)c[16*i+13] << 8) | ((unsigned)c[16*i+14] << 16) | ((unsigned)c[16*i+15] << 24);
      dst[i] = w4;
    }
    wsc[tid] = scale;
    lws[tid] = (float)log2((double)scale);
  }
}

// ---------------- main (r11-identical structure): 8n x 16o tile, 8-way K-split,
// 1024 threads, 2 blocks/CU
__global__ __launch_bounds__(1024, 8)
void msd_main_kernel(const unsigned short* __restrict__ xp,
                     const unsigned char* __restrict__ wq,
                     const float* __restrict__ xs, const float* __restrict__ lxs,
                     const float* __restrict__ wsc, const float* __restrict__ lws,
                     const float* __restrict__ bias, float* __restrict__ out) {
  __shared__ unsigned short sx[8][1032];    // row stride 2064B -> banks 4*tn apart
  __shared__ unsigned char  swq[16][1040];  // 2-way conflict only (free)
  __shared__ float sxs[8][33], slx[8][33], sws[16][33], slw[16][33];
  __shared__ float sred[7 * 128];
  const int tid = threadIdx.x;
  const int n0 = blockIdx.x * 8, o0 = blockIdx.y * 16;

  // stage x tile: 8 rows x 1024 packed ushorts (1 uint4 per thread)
  {
    int r = tid >> 7, c = tid & 127;
    uint4 d = ((const uint4*)(xp + (size_t)(n0 + r) * KDIM))[c];
    *(uint4*)&sx[r][c * 8] = d;
  }
  // stage w tile: 16 rows x 1024 bytes (1 uint4 per thread)
  {
    int r = tid >> 6, c = tid & 63;
    uint4 d = ((const uint4*)(wq + (size_t)(o0 + r) * KDIM))[c];
    *(uint4*)&swq[r][c * 16] = d;
  }
  {
    int r = tid >> 5, b = tid & 31;
    if (tid < 256) {
      sxs[r][b] = xs[(n0 + r) * NB + b];
      slx[r][b] = lxs[(n0 + r) * NB + b];
    }
    if (tid < 512) {
      sws[r][b] = wsc[(o0 + r) * NB + b];
      slw[r][b] = lws[(o0 + r) * NB + b];
    }
  }
  __syncthreads();

  const int kh = tid >> 7, idx = tid & 127, tn = idx >> 4, to = idx & 15;

  // e_max over blocks (combined_e = floor(lx + lw)) — proven scalar path
  float emf = -1e30f;
#pragma unroll
  for (int b = 0; b < NB; ++b)
    emf = fmaxf(emf, floorf(slx[tn][b] + slw[to][b]));
  const int iemax = (int)emf;
  // s = 32 - dbase = 24 + min(iemax,0) - ice   (dbase = 8+max(emax,0)-emax+ice)
  const int sbase = 24 + (iemax < 0 ? iemax : 0);

  float facc = 0.f;
  const int b0 = kh * 4;
#pragma unroll 1
  for (int bb = 0; bb < 4; ++bb) {
    const int b = b0 + bb;
    const int ice = (int)floorf(slx[tn][b] + slw[to][b]);
    const int s = sbase - ice;
    uint4 xv0 = *(const uint4*)&sx[tn][b * 32 + 0];
    uint4 xv1 = *(const uint4*)&sx[tn][b * 32 + 8];
    uint4 xv2 = *(const uint4*)&sx[tn][b * 32 + 16];
    uint4 xv3 = *(const uint4*)&sx[tn][b * 32 + 24];
    unsigned xd[16] = {xv0.x, xv0.y, xv0.z, xv0.w, xv1.x, xv1.y, xv1.z, xv1.w,
                       xv2.x, xv2.y, xv2.z, xv2.w, xv3.x, xv3.y, xv3.z, xv3.w};
    uint4 wv0 = *(const uint4*)&swq[to][b * 32];
    uint4 wv1 = *(const uint4*)&swq[to][b * 32 + 16];
    unsigned wb[8] = {wv0.x, wv0.y, wv0.z, wv0.w, wv1.x, wv1.y, wv1.z, wv1.w};
    int bacc = 0;
    int sc0, sc1, sc2, sc3, sc4;
#pragma unroll
    for (int j = 0; j < 16; ++j) {        // 2 elements per x-dword
      const unsigned xw = xd[j];
      const unsigned ww = wb[j >> 1];
      if ((j & 1) == 0) { NAF_PAIR(bacc, xw, ww, s, "0", "8"); }
      else              { NAF_PAIR(bacc, xw, ww, s, "16", "24"); }
    }
    facc += sxs[tn][b] * sws[to][b] * (float)bacc;  // exact: block_dot = bacc/4096
  }

  if (kh) sred[(kh - 1) * 128 + idx] = facc;
  __syncthreads();
  if (!kh) {
    float r = facc;
#pragma unroll
    for (int p = 0; p < 7; ++p) r += sred[p * 128 + idx];
    r = r * (1.0f / 4096.0f) + bias[o0 + to];
    out[(size_t)(n0 + tn) * ODIM + (o0 + to)] = r;
  }
}

extern "C" void kernel_launch(void* const* d_in, const int* in_sizes, int n_in,
                              void* d_out, int out_size, void* d_ws, size_t ws_size,
                              hipStream_t stream) {
  const float* x    = (const float*)d_in[0];
  const float* wgt  = (const float*)d_in[1];
  const float* bias = (const float*)d_in[2];
  float* out = (float*)d_out;
  char* ws = (char*)d_ws;
  // workspace layout (16B-aligned)
  unsigned short* xp  = (unsigned short*)(ws + 0);       // 262144 B
  unsigned char*  wq  = (unsigned char*)(ws + 262144);   // 524288 B
  float* xs  = (float*)(ws + 786432);
  float* lxs = (float*)(ws + 802816);
  float* wsc = (float*)(ws + 819200);
  float* lws = (float*)(ws + 884736);

  hipLaunchKernelGGL(prep_kernel, dim3(80), dim3(256), 0, stream,
                     x, wgt, xp, wq, xs, lxs, wsc, lws);
  hipLaunchKernelGGL(msd_main_kernel, dim3(16, 32), dim3(1024), 0, stream,
                     xp, wq, xs, lxs, wsc, lws, bias, out);
}

// Round 13
// 40.666 us; speedup vs baseline: 1.0476x; 1.0476x over previous
//
#include <hip/hip_runtime.h>
#include <math.h>

#define NROWS 128
#define KDIM  1024
#define ODIM  512
#define NB    32
#define BS    32

__device__ __forceinline__ int clz32(unsigned x) { return x ? __builtin_clz(x) : 32; }

// FROZEN (r11-verified, 37.3us/absmax 0.0078125): 11-inst asm core, one per op.
// kept = P - ((t&m)-(h&m)), m = 2^drop-1, h=P>>1, t=P+h,
// drop = clamp(isum - clz((t^h)|1), 0, 31).  Small-granularity asm: compiler
// schedules around it (r12's fused 34-inst block regressed 5us).
__device__ __forceinline__ int naf_keep(int P, int isum) {
  int kept, h, t, c, dr;
  asm volatile(
      "v_ashrrev_i32 %1, 1, %5\n\t"    // h  = P >> 1 (arith)
      "v_add_u32     %2, %5, %1\n\t"   // t  = P + h
      "v_xor_b32     %3, %2, %1\n\t"   // c  = t ^ h
      "v_or_b32      %3, 1, %3\n\t"    // c |= 1
      "v_ffbh_u32    %3, %3\n\t"       // c  = clz(c)
      "v_sub_u32     %4, %6, %3\n\t"   // dr = isum - c
      "v_med3_i32    %4, %4, 0, 31\n\t"// dr = clamp(dr, 0, 31)
      "v_bfe_u32     %3, %2, 0, %4\n\t"// c  = t & m
      "v_bfe_u32     %2, %1, 0, %4\n\t"// t' = h & m
      "v_sub_u32     %3, %3, %2\n\t"   // dropped = (t&m)-(h&m)
      "v_sub_u32     %0, %5, %3\n\t"   // kept = P - dropped
      : "=v"(kept), "=&v"(h), "=&v"(t), "=&v"(c), "=&v"(dr)
      : "v"(P), "v"(isum));
  return kept;
}

// ---------------- prep: wave-cooperative, fully coalesced.
// Wave W<64: x rows [2W, 2W+1].  Wave W>=64: w rows [2(W-64), 2(W-64)+1].
// Per load step j, 64 lanes read 1KB contiguous; 8-lane group g = one 32-float
// MX block; lane owns 4 floats.  Group max via shfl_xor (exact), quantize,
// pack, coalesced store.  Outputs bit-identical to the r11 per-thread prep.
__global__ __launch_bounds__(256)
void prep_kernel(const float* __restrict__ x, const float* __restrict__ wgt,
                 unsigned short* __restrict__ xp, unsigned char* __restrict__ wq,
                 float* __restrict__ xs, float* __restrict__ lxs,
                 float* __restrict__ wsc, float* __restrict__ lws) {
  const int W = blockIdx.x * 4 + (threadIdx.x >> 6);   // 0..319
  const int lane = threadIdx.x & 63;
  const int l8 = lane & 7;
  if (W < 64) {
    const int row0 = W * 2;
    const float4* src = (const float4*)(x + (size_t)row0 * KDIM);
#pragma unroll
    for (int j = 0; j < 8; ++j) {
      float4 f = src[j * 64 + lane];
      const int F = j * 256 + lane * 4;          // float index within row pair
      const int row = row0 + (F >> 10), blk = (F >> 5) & 31;
      float m = fmaxf(fmaxf(fabsf(f.x), fabsf(f.y)), fmaxf(fabsf(f.z), fabsf(f.w)));
      m = fmaxf(m, __shfl_xor(m, 1, 64));
      m = fmaxf(m, __shfl_xor(m, 2, 64));
      m = fmaxf(m, __shfl_xor(m, 4, 64));        // block max (exact)
      const float scale = fmaxf(m / 1.984375f, 1e-30f);
      const float vv[4] = {f.x, f.y, f.z, f.w};
      int q[4], e[4], em = -60;
#pragma unroll
      for (int i = 0; i < 4; ++i) {
        float t = vv[i] / scale * 64.0f;         // IEEE div, matches ref
        int qi = (int)rintf(t);                  // round-half-even
        q[i] = qi;
        int a = qi < 0 ? -qi : qi;
        e[i] = a ? (31 - clz32((unsigned)a)) - 6 : -60;
        em = e[i] > em ? e[i] : em;
      }
      em = max(em, __shfl_xor(em, 1, 64));
      em = max(em, __shfl_xor(em, 2, 64));
      em = max(em, __shfl_xor(em, 4, 64));       // block emax (exact)
      unsigned u0 = (unsigned)(unsigned short)(((em - e[0]) << 8) | (q[0] & 0xFF))
                  | ((unsigned)(unsigned short)(((em - e[1]) << 8) | (q[1] & 0xFF)) << 16);
      unsigned u1 = (unsigned)(unsigned short)(((em - e[2]) << 8) | (q[2] & 0xFF))
                  | ((unsigned)(unsigned short)(((em - e[3]) << 8) | (q[3] & 0xFF)) << 16);
      *(uint2*)(xp + (size_t)row * KDIM + blk * BS + l8 * 4) = make_uint2(u0, u1);
      if (l8 == 0) {
        xs[row * NB + blk] = scale;
        lxs[row * NB + blk] = (float)log2((double)scale);
      }
    }
  } else {
    const int row0 = (W - 64) * 2;
    const float4* src = (const float4*)(wgt + (size_t)row0 * KDIM);
#pragma unroll
    for (int j = 0; j < 8; ++j) {
      float4 f = src[j * 64 + lane];
      const int F = j * 256 + lane * 4;
      const int row = row0 + (F >> 10), blk = (F >> 5) & 31;
      float m = fmaxf(fmaxf(fabsf(f.x), fabsf(f.y)), fmaxf(fabsf(f.z), fabsf(f.w)));
      m = fmaxf(m, __shfl_xor(m, 1, 64));
      m = fmaxf(m, __shfl_xor(m, 2, 64));
      m = fmaxf(m, __shfl_xor(m, 4, 64));
      const float scale = fmaxf(m / 1.984375f, 1e-30f);
      const float vv[4] = {f.x, f.y, f.z, f.w};
      unsigned pk = 0;
#pragma unroll
      for (int i = 0; i < 4; ++i) {
        float t = vv[i] / scale * 64.0f;
        int qi = (int)rintf(t);
        pk |= ((unsigned)(qi & 0xFF)) << (8 * i);
      }
      *(unsigned*)(wq + (size_t)row * KDIM + blk * BS + l8 * 4) = pk;
      if (l8 == 0) {
        wsc[row * NB + blk] = scale;
        lws[row * NB + blk] = (float)log2((double)scale);
      }
    }
  }
}

// ---------------- main (r11 VERBATIM): 8n x 16o tile, 8-way K-split,
// 1024 threads, 2 blocks/CU
__global__ __launch_bounds__(1024, 8)
void msd_main_kernel(const unsigned short* __restrict__ xp,
                     const unsigned char* __restrict__ wq,
                     const float* __restrict__ xs, const float* __restrict__ lxs,
                     const float* __restrict__ wsc, const float* __restrict__ lws,
                     const float* __restrict__ bias, float* __restrict__ out) {
  __shared__ unsigned short sx[8][1032];    // row stride 2064B -> banks 4*tn apart
  __shared__ unsigned char  swq[16][1040];  // 2-way conflict only (free)
  __shared__ float sxs[8][33], slx[8][33], sws[16][33], slw[16][33];
  __shared__ float sred[7 * 128];
  const int tid = threadIdx.x;
  const int n0 = blockIdx.x * 8, o0 = blockIdx.y * 16;

  // stage x tile: 8 rows x 1024 packed ushorts (1 uint4 per thread)
  {
    int r = tid >> 7, c = tid & 127;
    uint4 d = ((const uint4*)(xp + (size_t)(n0 + r) * KDIM))[c];
    *(uint4*)&sx[r][c * 8] = d;
  }
  // stage w tile: 16 rows x 1024 bytes (1 uint4 per thread)
  {
    int r = tid >> 6, c = tid & 63;
    uint4 d = ((const uint4*)(wq + (size_t)(o0 + r) * KDIM))[c];
    *(uint4*)&swq[r][c * 16] = d;
  }
  {
    int r = tid >> 5, b = tid & 31;
    if (tid < 256) {
      sxs[r][b] = xs[(n0 + r) * NB + b];
      slx[r][b] = lxs[(n0 + r) * NB + b];
    }
    if (tid < 512) {
      sws[r][b] = wsc[(o0 + r) * NB + b];
      slw[r][b] = lws[(o0 + r) * NB + b];
    }
  }
  __syncthreads();

  const int kh = tid >> 7, idx = tid & 127, tn = idx >> 4, to = idx & 15;

  // e_max over blocks (combined_e = floor(lx + lw)) — proven scalar path
  float emf = -1e30f;
#pragma unroll
  for (int b = 0; b < NB; ++b)
    emf = fmaxf(emf, floorf(slx[tn][b] + slw[to][b]));
  const int iemax = (int)emf;
  // s = 32 - dbase = 24 + min(iemax,0) - ice   (dbase = 8+max(emax,0)-emax+ice)
  const int sbase = 24 + (iemax < 0 ? iemax : 0);

  float facc = 0.f;
  const int b0 = kh * 4;
#pragma unroll 1
  for (int bb = 0; bb < 4; ++bb) {
    const int b = b0 + bb;
    const int ice = (int)floorf(slx[tn][b] + slw[to][b]);
    const int s = sbase - ice;
    uint4 xv0 = *(const uint4*)&sx[tn][b * 32 + 0];
    uint4 xv1 = *(const uint4*)&sx[tn][b * 32 + 8];
    uint4 xv2 = *(const uint4*)&sx[tn][b * 32 + 16];
    uint4 xv3 = *(const uint4*)&sx[tn][b * 32 + 24];
    unsigned xd[16] = {xv0.x, xv0.y, xv0.z, xv0.w, xv1.x, xv1.y, xv1.z, xv1.w,
                       xv2.x, xv2.y, xv2.z, xv2.w, xv3.x, xv3.y, xv3.z, xv3.w};
    uint4 wv0 = *(const uint4*)&swq[to][b * 32];
    uint4 wv1 = *(const uint4*)&swq[to][b * 32 + 16];
    unsigned wb[8] = {wv0.x, wv0.y, wv0.z, wv0.w, wv1.x, wv1.y, wv1.z, wv1.w};
    int bacc = 0;
#pragma unroll
    for (int j = 0; j < 16; ++j) {        // 2 elements per x-dword
      const unsigned xw = xd[j];
      const unsigned ww = wb[j >> 1];
      const int ix0 = __builtin_amdgcn_sbfe((int)xw, 0, 8);      // v_bfe_i32
      const int in0 = (int)__builtin_amdgcn_ubfe(xw, 8, 8);      // v_bfe_u32
      const int ix1 = __builtin_amdgcn_sbfe((int)xw, 16, 8);
      const int in1 = (int)(xw >> 24);
      int iw0, iw1;
      if (j & 1) { iw0 = __builtin_amdgcn_sbfe((int)ww, 16, 8);
                   iw1 = __builtin_amdgcn_sbfe((int)ww, 24, 8); }
      else       { iw0 = __builtin_amdgcn_sbfe((int)ww, 0, 8);
                   iw1 = __builtin_amdgcn_sbfe((int)ww, 8, 8); }
      bacc += naf_keep(__mul24(ix0, iw0), in0 + s);     // |ix|,|iw| <= 127: exact
      bacc += naf_keep(__mul24(ix1, iw1), in1 + s);
    }
    facc += sxs[tn][b] * sws[to][b] * (float)bacc;  // exact: block_dot = bacc/4096
  }

  if (kh) sred[(kh - 1) * 128 + idx] = facc;
  __syncthreads();
  if (!kh) {
    float r = facc;
#pragma unroll
    for (int p = 0; p < 7; ++p) r += sred[p * 128 + idx];
    r = r * (1.0f / 4096.0f) + bias[o0 + to];
    out[(size_t)(n0 + tn) * ODIM + (o0 + to)] = r;
  }
}

extern "C" void kernel_launch(void* const* d_in, const int* in_sizes, int n_in,
                              void* d_out, int out_size, void* d_ws, size_t ws_size,
                              hipStream_t stream) {
  const float* x    = (const float*)d_in[0];
  const float* wgt  = (const float*)d_in[1];
  const float* bias = (const float*)d_in[2];
  float* out = (float*)d_out;
  char* ws = (char*)d_ws;
  // workspace layout (16B-aligned)
  unsigned short* xp  = (unsigned short*)(ws + 0);       // 262144 B
  unsigned char*  wq  = (unsigned char*)(ws + 262144);   // 524288 B
  float* xs  = (float*)(ws + 786432);
  float* lxs = (float*)(ws + 802816);
  float* wsc = (float*)(ws + 819200);
  float* lws = (float*)(ws + 884736);

  hipLaunchKernelGGL(prep_kernel, dim3(80), dim3(256), 0, stream,
                     x, wgt, xp, wq, xs, lxs, wsc, lws);
  hipLaunchKernelGGL(msd_main_kernel, dim3(16, 32), dim3(1024), 0, stream,
                     xp, wq, xs, lxs, wsc, lws, bias, out);
}

// Round 14
// 40.392 us; speedup vs baseline: 1.0547x; 1.0068x over previous
//
#include <hip/hip_runtime.h>
#include <math.h>

#define NROWS 128
#define KDIM  1024
#define ODIM  512
#define NB    32
#define BS    32

__device__ __forceinline__ int clz32(unsigned x) { return x ? __builtin_clz(x) : 32; }

// FROZEN (r11-verified, 37.3us/absmax 0.0078125): 11-inst asm core, one per op.
// kept = P - ((t&m)-(h&m)), m = 2^drop-1, h=P>>1, t=P+h,
// drop = clamp(isum - clz((t^h)|1), 0, 31).  Small-granularity asm: compiler
// schedules around it (r12's fused 34-inst block regressed 5us).
__device__ __forceinline__ int naf_keep(int P, int isum) {
  int kept, h, t, c, dr;
  asm volatile(
      "v_ashrrev_i32 %1, 1, %5\n\t"    // h  = P >> 1 (arith)
      "v_add_u32     %2, %5, %1\n\t"   // t  = P + h
      "v_xor_b32     %3, %2, %1\n\t"   // c  = t ^ h
      "v_or_b32      %3, 1, %3\n\t"    // c |= 1
      "v_ffbh_u32    %3, %3\n\t"       // c  = clz(c)
      "v_sub_u32     %4, %6, %3\n\t"   // dr = isum - c
      "v_med3_i32    %4, %4, 0, 31\n\t"// dr = clamp(dr, 0, 31)
      "v_bfe_u32     %3, %2, 0, %4\n\t"// c  = t & m
      "v_bfe_u32     %2, %1, 0, %4\n\t"// t' = h & m
      "v_sub_u32     %3, %3, %2\n\t"   // dropped = (t&m)-(h&m)
      "v_sub_u32     %0, %5, %3\n\t"   // kept = P - dropped
      : "=v"(kept), "=&v"(h), "=&v"(t), "=&v"(c), "=&v"(dr)
      : "v"(P), "v"(isum));
  return kept;
}

// ---------------- single fused kernel: 8n x 16o tile, 8-way K-split, 1024 thr.
// Prologue: threads 0..255 quantize this block's 8 x-rows (32 MX blocks each),
// threads 256..767 quantize its 16 w-rows — DIRECTLY into LDS (math verbatim
// from r11's prep => bit-identical values).  No global xp/wq, no 2nd launch.
__global__ __launch_bounds__(1024, 8)
void msd_fused_kernel(const float* __restrict__ x, const float* __restrict__ wgt,
                      const float* __restrict__ bias, float* __restrict__ out) {
  __shared__ unsigned short sx[8][1032];    // row stride 2064B -> banks 4*tn apart
  __shared__ unsigned char  swq[16][1040];  // 2-way conflict only (free)
  __shared__ float sxs[8][33], slx[8][33], sws[16][33], slw[16][33];
  __shared__ float sred[7 * 128];
  const int tid = threadIdx.x;
  const int n0 = blockIdx.x * 8, o0 = blockIdx.y * 16;

  if (tid < 256) {
    // ---- x quant task: r = tid>>5 (row n0+r), b = tid&31 (MX block) ----
    const int r = tid >> 5, b = tid & 31;
    const float4* p = (const float4*)(x + (size_t)(n0 + r) * KDIM + b * BS);
    float4 f[8];
    float m = 0.f;
#pragma unroll
    for (int i = 0; i < 8; ++i) {
      f[i] = p[i];
      m = fmaxf(m, fmaxf(fmaxf(fabsf(f[i].x), fabsf(f[i].y)),
                         fmaxf(fabsf(f[i].z), fabsf(f[i].w))));
    }
    const float scale = fmaxf(m / 1.984375f, 1e-30f);
    // sweep: pack (e+60)<<8 | (q&0xFF) halfwords into uw[16]; track emax.
    unsigned uw[16];
    int emax = -60;
#pragma unroll
    for (int i = 0; i < 32; ++i) {
      const float vi = (i & 3) == 0 ? f[i >> 2].x
                     : (i & 3) == 1 ? f[i >> 2].y
                     : (i & 3) == 2 ? f[i >> 2].z : f[i >> 2].w;
      float t = vi / scale * 64.0f;     // IEEE div + exact pow2 mul, matches ref
      int qi = (int)rintf(t);           // round-half-even, matches jnp.round
      int a = qi < 0 ? -qi : qi;
      int ei = a ? (31 - clz32((unsigned)a)) - 6 : -60;
      emax = ei > emax ? ei : emax;
      unsigned entry = (((unsigned)(ei + 60)) << 8) | ((unsigned)qi & 0xFFu);
      if ((i & 1) == 0) uw[i >> 1] = entry;
      else              uw[i >> 1] |= entry << 16;
    }
    // fixup sweep: intra = (emax+60) - e60; write 4 uint4 into LDS.
    const unsigned emax60 = (unsigned)(emax + 60);
#pragma unroll
    for (int g = 0; g < 4; ++g) {
      unsigned wd[4];
#pragma unroll
      for (int k = 0; k < 4; ++k) {
        const unsigned w = uw[g * 4 + k];
        const unsigned lo = ((emax60 - ((w >> 8) & 0xFFu)) << 8) | (w & 0xFFu);
        const unsigned hi = ((emax60 - (w >> 24)) << 8) | ((w >> 16) & 0xFFu);
        wd[k] = lo | (hi << 16);
      }
      *(uint4*)&sx[r][b * 32 + g * 8] = make_uint4(wd[0], wd[1], wd[2], wd[3]);
    }
    sxs[r][b] = scale;
    slx[r][b] = (float)log2((double)scale);
  } else if (tid < 768) {
    // ---- w quant task: r = (tid-256)>>5 (row o0+r), b = (tid-256)&31 ----
    const int t2 = tid - 256;
    const int r = t2 >> 5, b = t2 & 31;
    const float4* p = (const float4*)(wgt + (size_t)(o0 + r) * KDIM + b * BS);
    float4 f[8];
    float m = 0.f;
#pragma unroll
    for (int i = 0; i < 8; ++i) {
      f[i] = p[i];
      m = fmaxf(m, fmaxf(fmaxf(fabsf(f[i].x), fabsf(f[i].y)),
                         fmaxf(fabsf(f[i].z), fabsf(f[i].w))));
    }
    const float scale = fmaxf(m / 1.984375f, 1e-30f);
    unsigned cw[8];
#pragma unroll
    for (int i = 0; i < 32; ++i) {
      const float vi = (i & 3) == 0 ? f[i >> 2].x
                     : (i & 3) == 1 ? f[i >> 2].y
                     : (i & 3) == 2 ? f[i >> 2].z : f[i >> 2].w;
      float t = vi / scale * 64.0f;
      int qi = (int)rintf(t);
      unsigned byte = (unsigned)qi & 0xFFu;
      if ((i & 3) == 0) cw[i >> 2] = byte;
      else              cw[i >> 2] |= byte << (8 * (i & 3));
    }
    *(uint4*)&swq[r][b * 32]      = make_uint4(cw[0], cw[1], cw[2], cw[3]);
    *(uint4*)&swq[r][b * 32 + 16] = make_uint4(cw[4], cw[5], cw[6], cw[7]);
    sws[r][b] = scale;
    slw[r][b] = (float)log2((double)scale);
  }
  __syncthreads();

  // ---------------- r11 main body VERBATIM from here ----------------
  const int kh = tid >> 7, idx = tid & 127, tn = idx >> 4, to = idx & 15;

  // e_max over blocks (combined_e = floor(lx + lw)) — proven scalar path
  float emf = -1e30f;
#pragma unroll
  for (int b = 0; b < NB; ++b)
    emf = fmaxf(emf, floorf(slx[tn][b] + slw[to][b]));
  const int iemax = (int)emf;
  // s = 32 - dbase = 24 + min(iemax,0) - ice   (dbase = 8+max(emax,0)-emax+ice)
  const int sbase = 24 + (iemax < 0 ? iemax : 0);

  float facc = 0.f;
  const int b0 = kh * 4;
#pragma unroll 1
  for (int bb = 0; bb < 4; ++bb) {
    const int b = b0 + bb;
    const int ice = (int)floorf(slx[tn][b] + slw[to][b]);
    const int s = sbase - ice;
    uint4 xv0 = *(const uint4*)&sx[tn][b * 32 + 0];
    uint4 xv1 = *(const uint4*)&sx[tn][b * 32 + 8];
    uint4 xv2 = *(const uint4*)&sx[tn][b * 32 + 16];
    uint4 xv3 = *(const uint4*)&sx[tn][b * 32 + 24];
    unsigned xd[16] = {xv0.x, xv0.y, xv0.z, xv0.w, xv1.x, xv1.y, xv1.z, xv1.w,
                       xv2.x, xv2.y, xv2.z, xv2.w, xv3.x, xv3.y, xv3.z, xv3.w};
    uint4 wv0 = *(const uint4*)&swq[to][b * 32];
    uint4 wv1 = *(const uint4*)&swq[to][b * 32 + 16];
    unsigned wb[8] = {wv0.x, wv0.y, wv0.z, wv0.w, wv1.x, wv1.y, wv1.z, wv1.w};
    int bacc = 0;
#pragma unroll
    for (int j = 0; j < 16; ++j) {        // 2 elements per x-dword
      const unsigned xw = xd[j];
      const unsigned ww = wb[j >> 1];
      const int ix0 = __builtin_amdgcn_sbfe((int)xw, 0, 8);      // v_bfe_i32
      const int in0 = (int)__builtin_amdgcn_ubfe(xw, 8, 8);      // v_bfe_u32
      const int ix1 = __builtin_amdgcn_sbfe((int)xw, 16, 8);
      const int in1 = (int)(xw >> 24);
      int iw0, iw1;
      if (j & 1) { iw0 = __builtin_amdgcn_sbfe((int)ww, 16, 8);
                   iw1 = __builtin_amdgcn_sbfe((int)ww, 24, 8); }
      else       { iw0 = __builtin_amdgcn_sbfe((int)ww, 0, 8);
                   iw1 = __builtin_amdgcn_sbfe((int)ww, 8, 8); }
      bacc += naf_keep(__mul24(ix0, iw0), in0 + s);     // |ix|,|iw| <= 127: exact
      bacc += naf_keep(__mul24(ix1, iw1), in1 + s);
    }
    facc += sxs[tn][b] * sws[to][b] * (float)bacc;  // exact: block_dot = bacc/4096
  }

  if (kh) sred[(kh - 1) * 128 + idx] = facc;
  __syncthreads();
  if (!kh) {
    float r = facc;
#pragma unroll
    for (int p = 0; p < 7; ++p) r += sred[p * 128 + idx];
    r = r * (1.0f / 4096.0f) + bias[o0 + to];
    out[(size_t)(n0 + tn) * ODIM + (o0 + to)] = r;
  }
}

extern "C" void kernel_launch(void* const* d_in, const int* in_sizes, int n_in,
                              void* d_out, int out_size, void* d_ws, size_t ws_size,
                              hipStream_t stream) {
  const float* x    = (const float*)d_in[0];
  const float* wgt  = (const float*)d_in[1];
  const float* bias = (const float*)d_in[2];
  float* out = (float*)d_out;
  (void)d_ws; (void)ws_size;   // workspace no longer needed

  hipLaunchKernelGGL(msd_fused_kernel, dim3(16, 32), dim3(1024), 0, stream,
                     x, wgt, bias, out);
}

// Round 15
// 35.492 us; speedup vs baseline: 1.2003x; 1.1380x over previous
//
#include <hip/hip_runtime.h>
#include <math.h>

#define NROWS 128
#define KDIM  1024
#define ODIM  512
#define NB    32
#define BS    32

__device__ __forceinline__ int clz32(unsigned x) { return x ? __builtin_clz(x) : 32; }

// FROZEN SEMANTICS (r7-r11): kept value of P after dropping the low
// (width - d) NAF digits.  h=P>>1 (arith), t=P+h, dr=clamp(isum-clz(t^h),0,31).
// r15 form: kept = (t & ~m) - (h & ~m), ~m = -1<<dr  — exact by bit-partition
// x=(x&m)+(x&~m); equals r11's P-((t&m)-(h&m)) for all P,dr (edges dr=0: kept=P;
// dr=31: kept=0; P=0: t=h=0 -> kept=0, ffbh(0)=-1 benign).  Hand-asm: the
// r3/r4/r6 compiler mis-fold hazard cannot apply here.
// %7 = all-ones VGPR (~0), materialized once outside the loop.
__device__ __forceinline__ int naf_keep(int P, int isum, int allones) {
  int kept, h, t, c, dr;
  asm volatile(
      "v_ashrrev_i32 %1, 1, %5\n\t"     // h  = P >> 1 (arith)
      "v_add_u32     %2, %5, %1\n\t"    // t  = P + h
      "v_xor_b32     %3, %2, %1\n\t"    // c  = t ^ h
      "v_ffbh_u32    %3, %3\n\t"        // c  = clz(c)   (-1 if c==0 -> benign)
      "v_sub_u32     %4, %6, %3\n\t"    // dr = isum - c
      "v_med3_i32    %4, %4, 0, 31\n\t" // dr = clamp(dr, 0, 31)
      "v_lshlrev_b32 %3, %4, %7\n\t"    // c  = ~m = (-1) << dr  (src1 = VGPR)
      "v_and_b32     %2, %2, %3\n\t"    // t &= ~m
      "v_and_b32     %1, %1, %3\n\t"    // h &= ~m
      "v_sub_u32     %0, %2, %1"        // kept = (t&~m) - (h&~m)
      : "=v"(kept), "=&v"(h), "=&v"(t), "=&v"(c), "=&v"(dr)
      : "v"(P), "v"(isum), "v"(allones));
  return kept;
}

// ---------------- merged prep (r9/r11-identical): blocks 0..15 x, 16..79 w
__global__ void prep_kernel(const float* __restrict__ x, const float* __restrict__ wgt,
                            unsigned short* __restrict__ xp, unsigned char* __restrict__ wq,
                            float* __restrict__ xs, float* __restrict__ lxs,
                            float* __restrict__ wsc, float* __restrict__ lws) {
  const int bid = blockIdx.x;
  if (bid < 16) {
    int tid = bid * 256 + threadIdx.x;            // 0..4095 = 128 rows x 32 blocks
    int row = tid >> 5, blk = tid & 31;
    const float4* p = (const float4*)(x + (size_t)row * KDIM + blk * BS);
    float v[32];
    float m = 0.f;
#pragma unroll
    for (int i = 0; i < 8; ++i) {
      float4 f = p[i];
      v[4*i+0] = f.x; v[4*i+1] = f.y; v[4*i+2] = f.z; v[4*i+3] = f.w;
      m = fmaxf(m, fmaxf(fmaxf(fabsf(f.x), fabsf(f.y)), fmaxf(fabsf(f.z), fabsf(f.w))));
    }
    float scale = fmaxf(m / 1.984375f, 1e-30f);
    int q[32], e[32], emax = -60;
#pragma unroll
    for (int i = 0; i < 32; ++i) {
      float t = v[i] / scale * 64.0f;     // IEEE div + exact pow2 mul, matches ref
      int qi = (int)rintf(t);             // round-half-even, matches jnp.round
      q[i] = qi;
      int a = qi < 0 ? -qi : qi;
      int ei = a ? (31 - clz32((unsigned)a)) - 6 : -60;
      e[i] = ei;
      emax = ei > emax ? ei : emax;
    }
    unsigned short u[32];
#pragma unroll
    for (int i = 0; i < 32; ++i)
      u[i] = (unsigned short)(((emax - e[i]) << 8) | (q[i] & 0xFF));
    uint4* dst = (uint4*)(xp + (size_t)row * KDIM + blk * BS);
#pragma unroll
    for (int i = 0; i < 4; ++i) {
      uint4 w4;
      w4.x = (unsigned)u[8*i+0] | ((unsigned)u[8*i+1] << 16);
      w4.y = (unsigned)u[8*i+2] | ((unsigned)u[8*i+3] << 16);
      w4.z = (unsigned)u[8*i+4] | ((unsigned)u[8*i+5] << 16);
      w4.w = (unsigned)u[8*i+6] | ((unsigned)u[8*i+7] << 16);
      dst[i] = w4;
    }
    xs[tid] = scale;
    lxs[tid] = (float)log2((double)scale);
  } else {
    int tid = (bid - 16) * 256 + threadIdx.x;     // 0..16383 = 512 rows x 32 blocks
    int row = tid >> 5, blk = tid & 31;
    const float4* p = (const float4*)(wgt + (size_t)row * KDIM + blk * BS);
    float v[32];
    float m = 0.f;
#pragma unroll
    for (int i = 0; i < 8; ++i) {
      float4 f = p[i];
      v[4*i+0] = f.x; v[4*i+1] = f.y; v[4*i+2] = f.z; v[4*i+3] = f.w;
      m = fmaxf(m, fmaxf(fmaxf(fabsf(f.x), fabsf(f.y)), fmaxf(fabsf(f.z), fabsf(f.w))));
    }
    float scale = fmaxf(m / 1.984375f, 1e-30f);
    unsigned char c[32];
#pragma unroll
    for (int i = 0; i < 32; ++i) {
      float t = v[i] / scale * 64.0f;
      int qi = (int)rintf(t);
      c[i] = (unsigned char)(qi & 0xFF);
    }
    uint4* dst = (uint4*)(wq + (size_t)row * KDIM + blk * BS);
#pragma unroll
    for (int i = 0; i < 2; ++i) {
      uint4 w4;
      w4.x = (unsigned)c[16*i+ 0] | ((unsigned)c[16*i+ 1] << 8) | ((unsigned)c[16*i+ 2] << 16) | ((unsigned)c[16*i+ 3] << 24);
      w4.y = (unsigned)c[16*i+ 4] | ((unsigned)c[16*i+ 5] << 8) | ((unsigned)c[16*i+ 6] << 16) | ((unsigned)c[16*i+ 7] << 24);
      w4.z = (unsigned)c[16*i+ 8] | ((unsigned)c[16*i+ 9] << 8) | ((unsigned)c[16*i+10] << 16) | ((unsigned)c[16*i+11] << 24);
      w4.w = (unsigned)c[16*i+12] | ((unsigned)c[16*i+13] << 8) | ((unsigned)c[16*i+14] << 16) | ((unsigned)c[16*i+15] << 24);
      dst[i] = w4;
    }
    wsc[tid] = scale;
    lws[tid] = (float)log2((double)scale);
  }
}

// ---------------- main (r11 structure verbatim): 8n x 16o tile, 8-way K-split,
// 1024 threads, 2 blocks/CU
__global__ __launch_bounds__(1024, 8)
void msd_main_kernel(const unsigned short* __restrict__ xp,
                     const unsigned char* __restrict__ wq,
                     const float* __restrict__ xs, const float* __restrict__ lxs,
                     const float* __restrict__ wsc, const float* __restrict__ lws,
                     const float* __restrict__ bias, float* __restrict__ out) {
  __shared__ unsigned short sx[8][1032];    // row stride 2064B -> banks 4*tn apart
  __shared__ unsigned char  swq[16][1040];  // 2-way conflict only (free)
  __shared__ float sxs[8][33], slx[8][33], sws[16][33], slw[16][33];
  __shared__ float sred[7 * 128];
  const int tid = threadIdx.x;
  const int n0 = blockIdx.x * 8, o0 = blockIdx.y * 16;

  // stage x tile: 8 rows x 1024 packed ushorts (1 uint4 per thread)
  {
    int r = tid >> 7, c = tid & 127;
    uint4 d = ((const uint4*)(xp + (size_t)(n0 + r) * KDIM))[c];
    *(uint4*)&sx[r][c * 8] = d;
  }
  // stage w tile: 16 rows x 1024 bytes (1 uint4 per thread)
  {
    int r = tid >> 6, c = tid & 63;
    uint4 d = ((const uint4*)(wq + (size_t)(o0 + r) * KDIM))[c];
    *(uint4*)&swq[r][c * 16] = d;
  }
  {
    int r = tid >> 5, b = tid & 31;
    if (tid < 256) {
      sxs[r][b] = xs[(n0 + r) * NB + b];
      slx[r][b] = lxs[(n0 + r) * NB + b];
    }
    if (tid < 512) {
      sws[r][b] = wsc[(o0 + r) * NB + b];
      slw[r][b] = lws[(o0 + r) * NB + b];
    }
  }
  __syncthreads();

  const int kh = tid >> 7, idx = tid & 127, tn = idx >> 4, to = idx & 15;

  // e_max over blocks (combined_e = floor(lx + lw)) — proven scalar path
  float emf = -1e30f;
#pragma unroll
  for (int b = 0; b < NB; ++b)
    emf = fmaxf(emf, floorf(slx[tn][b] + slw[to][b]));
  const int iemax = (int)emf;
  // s = 32 - dbase = 24 + min(iemax,0) - ice   (dbase = 8+max(emax,0)-emax+ice)
  const int sbase = 24 + (iemax < 0 ? iemax : 0);

  const int allones = (int)0xFFFFFFFF;   // VGPR-materialized once, feeds asm %7

  float facc = 0.f;
  const int b0 = kh * 4;
#pragma unroll 1
  for (int bb = 0; bb < 4; ++bb) {
    const int b = b0 + bb;
    const int ice = (int)floorf(slx[tn][b] + slw[to][b]);
    const int s = sbase - ice;
    uint4 xv0 = *(const uint4*)&sx[tn][b * 32 + 0];
    uint4 xv1 = *(const uint4*)&sx[tn][b * 32 + 8];
    uint4 xv2 = *(const uint4*)&sx[tn][b * 32 + 16];
    uint4 xv3 = *(const uint4*)&sx[tn][b * 32 + 24];
    unsigned xd[16] = {xv0.x, xv0.y, xv0.z, xv0.w, xv1.x, xv1.y, xv1.z, xv1.w,
                       xv2.x, xv2.y, xv2.z, xv2.w, xv3.x, xv3.y, xv3.z, xv3.w};
    uint4 wv0 = *(const uint4*)&swq[to][b * 32];
    uint4 wv1 = *(const uint4*)&swq[to][b * 32 + 16];
    unsigned wb[8] = {wv0.x, wv0.y, wv0.z, wv0.w, wv1.x, wv1.y, wv1.z, wv1.w};
    int bacc = 0;
#pragma unroll
    for (int j = 0; j < 16; ++j) {        // 2 elements per x-dword
      const unsigned xw = xd[j];
      const unsigned ww = wb[j >> 1];
      const int ix0 = __builtin_amdgcn_sbfe((int)xw, 0, 8);      // v_bfe_i32
      const int in0 = (int)__builtin_amdgcn_ubfe(xw, 8, 8);      // v_bfe_u32
      const int ix1 = __builtin_amdgcn_sbfe((int)xw, 16, 8);
      const int in1 = (int)(xw >> 24);
      int iw0, iw1;
      if (j & 1) { iw0 = __builtin_amdgcn_sbfe((int)ww, 16, 8);
                   iw1 = __builtin_amdgcn_sbfe((int)ww, 24, 8); }
      else       { iw0 = __builtin_amdgcn_sbfe((int)ww, 0, 8);
                   iw1 = __builtin_amdgcn_sbfe((int)ww, 8, 8); }
      bacc += naf_keep(__mul24(ix0, iw0), in0 + s, allones);   // |ix|,|iw|<=127
      bacc += naf_keep(__mul24(ix1, iw1), in1 + s, allones);
    }
    facc += sxs[tn][b] * sws[to][b] * (float)bacc;  // exact: block_dot = bacc/4096
  }

  if (kh) sred[(kh - 1) * 128 + idx] = facc;
  __syncthreads();
  if (!kh) {
    float r = facc;
#pragma unroll
    for (int p = 0; p < 7; ++p) r += sred[p * 128 + idx];
    r = r * (1.0f / 4096.0f) + bias[o0 + to];
    out[(size_t)(n0 + tn) * ODIM + (o0 + to)] = r;
  }
}

extern "C" void kernel_launch(void* const* d_in, const int* in_sizes, int n_in,
                              void* d_out, int out_size, void* d_ws, size_t ws_size,
                              hipStream_t stream) {
  const float* x    = (const float*)d_in[0];
  const float* wgt  = (const float*)d_in[1];
  const float* bias = (const float*)d_in[2];
  float* out = (float*)d_out;
  char* ws = (char*)d_ws;
  // workspace layout (16B-aligned)
  unsigned short* xp  = (unsigned short*)(ws + 0);       // 262144 B
  unsigned char*  wq  = (unsigned char*)(ws + 262144);   // 524288 B
  float* xs  = (float*)(ws + 786432);
  float* lxs = (float*)(ws + 802816);
  float* wsc = (float*)(ws + 819200);
  float* lws = (float*)(ws + 884736);

  hipLaunchKernelGGL(prep_kernel, dim3(80), dim3(256), 0, stream,
                     x, wgt, xp, wq, xs, lxs, wsc, lws);
  hipLaunchKernelGGL(msd_main_kernel, dim3(16, 32), dim3(1024), 0, stream,
                     xp, wq, xs, lxs, wsc, lws, bias, out);
}